// Round 1
// baseline (867.369 us; speedup 1.0000x reference)
//
#include <hip/hip_runtime.h>
#include <math.h>

// ---- problem constants ----
#define CC   128
#define PP   256
#define NHH  8
#define HDD  32
#define HIDD 384
#define LL   196
#define NWW  128
#define BNN  256          // B*NW
#define TT   50176        // BNN*LL
#define DV   8
#define HV   56
#define WV   56

// =====================================================================
// K0: biasT[h][j][i] = rel_table[rel_idx[i][j]*NH + h]
// =====================================================================
__global__ __launch_bounds__(256) void k_bias(const float* __restrict__ tbl,
                                              const int* __restrict__ idx,
                                              float* __restrict__ biasT) {
    int t = blockIdx.x * 256 + threadIdx.x;
    if (t >= NHH * LL * LL) return;
    int i = t % LL;
    int j = (t / LL) % LL;
    int h = t / (LL * LL);
    biasT[t] = tbl[idx[i * LL + j] * NHH + h];
}

// =====================================================================
// K1: roll+partition gather + QKV projection.  blockIdx.y selects q/k/v.
// tile: 128 tokens x 256 cols, thread tile 8x16, K=128 in 4 chunks of 32.
// Output layout: [Bn][NH][L][HD].  mat==0 also writes residual [T][C].
// =====================================================================
__global__ __launch_bounds__(256) void k_qkv(
    const float* __restrict__ qsrc, const float* __restrict__ ksrc, const float* __restrict__ vsrc,
    const float* __restrict__ Wq, const float* __restrict__ bq,
    const float* __restrict__ Wk, const float* __restrict__ bk,
    const float* __restrict__ Wv, const float* __restrict__ bv,
    float* __restrict__ Qo, float* __restrict__ Ko, float* __restrict__ Vo,
    float* __restrict__ resid)
{
    const int mat = blockIdx.y;
    const float* __restrict__ src = (mat == 0) ? qsrc : ((mat == 1) ? ksrc : vsrc);
    const float* __restrict__ W   = (mat == 0) ? Wq   : ((mat == 1) ? Wk   : Wv);
    const float* __restrict__ bb  = (mat == 0) ? bq   : ((mat == 1) ? bk   : bv);
    float* __restrict__ out       = (mat == 0) ? Qo   : ((mat == 1) ? Ko   : Vo);

    __shared__ float xs[32][132];   // [k][token]
    __shared__ float wt[32][260];   // [k][col]
    __shared__ int s_off[128];
    __shared__ int s_bw[128];
    __shared__ int s_l[128];

    const int tid = threadIdx.x;
    const int m0 = blockIdx.x * 128;

    if (tid < 128) {
        int m = m0 + tid;
        int l = m % LL, bw = m / LL;
        int w = bw & (NWW - 1);
        int b = bw >> 7;
        int wd = w >> 6, wh = (w >> 3) & 7, ww = w & 7;
        int td = l / 49, r = l % 49, th = r / 7, tw = r % 7;
        int d  = wd * 4 + td + 2;  if (d  >= DV) d  -= DV;
        int hh = wh * 7 + th + 3;  if (hh >= HV) hh -= HV;
        int wc = ww * 7 + tw + 3;  if (wc >= WV) wc -= WV;
        s_off[tid] = (((b * DV + d) * HV + hh) * WV + wc) * CC;
        s_bw[tid] = bw;
        s_l[tid] = l;
    }

    const int tx = tid & 15, ty = tid >> 4;
    float acc[8][16];
#pragma unroll
    for (int t = 0; t < 8; t++)
#pragma unroll
        for (int c = 0; c < 16; c++) acc[t][c] = 0.f;

    for (int kc = 0; kc < 4; kc++) {
        __syncthreads();
        {   // stage x (transpose into xs) + residual write
            int tok = tid >> 1, half = tid & 1;
            const float* gp = src + s_off[tok] + kc * 32 + half * 16;
            float4 a0 = *(const float4*)(gp);
            float4 a1 = *(const float4*)(gp + 4);
            float4 a2 = *(const float4*)(gp + 8);
            float4 a3 = *(const float4*)(gp + 12);
            int kb = half * 16;
            xs[kb+ 0][tok] = a0.x; xs[kb+ 1][tok] = a0.y; xs[kb+ 2][tok] = a0.z; xs[kb+ 3][tok] = a0.w;
            xs[kb+ 4][tok] = a1.x; xs[kb+ 5][tok] = a1.y; xs[kb+ 6][tok] = a1.z; xs[kb+ 7][tok] = a1.w;
            xs[kb+ 8][tok] = a2.x; xs[kb+ 9][tok] = a2.y; xs[kb+10][tok] = a2.z; xs[kb+11][tok] = a2.w;
            xs[kb+12][tok] = a3.x; xs[kb+13][tok] = a3.y; xs[kb+14][tok] = a3.z; xs[kb+15][tok] = a3.w;
            if (mat == 0) {
                float* rp = resid + (size_t)(m0 + tok) * CC + kc * 32 + half * 16;
                *(float4*)(rp)      = a0;
                *(float4*)(rp + 4)  = a1;
                *(float4*)(rp + 8)  = a2;
                *(float4*)(rp + 12) = a3;
            }
        }
        {   // stage W chunk [32][256]
            const float4* wg = (const float4*)(W + (size_t)kc * 32 * PP);
#pragma unroll
            for (int u = 0; u < 8; u++) {
                int f = u * 256 + tid;
                int k = f >> 6, c4 = f & 63;
                *((float4*)&wt[k][c4 * 4]) = wg[f];
            }
        }
        __syncthreads();
#pragma unroll 4
        for (int k = 0; k < 32; k++) {
            float4 xa = *((const float4*)&xs[k][tx * 8]);
            float4 xb = *((const float4*)&xs[k][tx * 8 + 4]);
            float x8[8] = {xa.x, xa.y, xa.z, xa.w, xb.x, xb.y, xb.z, xb.w};
#pragma unroll
            for (int i = 0; i < 4; i++) {
                float4 wv = *((const float4*)&wt[k][(ty + 16 * i) * 4]);
#pragma unroll
                for (int t = 0; t < 8; t++) {
                    acc[t][i*4+0] += x8[t] * wv.x;
                    acc[t][i*4+1] += x8[t] * wv.y;
                    acc[t][i*4+2] += x8[t] * wv.z;
                    acc[t][i*4+3] += x8[t] * wv.w;
                }
            }
        }
    }

    // epilogue: +bias, write head-major [Bn][NH][L][HD]
#pragma unroll
    for (int i = 0; i < 4; i++) {
        int g = ty + 16 * i;
        int n0 = g * 4;
        int head = n0 >> 5, hd0 = n0 & 31;
        float4 bv4 = ((const float4*)bb)[g];
#pragma unroll
        for (int t = 0; t < 8; t++) {
            int mi = tx * 8 + t;
            size_t o = ((size_t)(s_bw[mi] * NHH + head) * LL + s_l[mi]) * HDD + hd0;
            float4 rr;
            rr.x = acc[t][i*4+0] + bv4.x;
            rr.y = acc[t][i*4+1] + bv4.y;
            rr.z = acc[t][i*4+2] + bv4.z;
            rr.w = acc[t][i*4+3] + bv4.w;
            *((float4*)(out + o)) = rr;
        }
    }
}

// =====================================================================
// K2: attention per (head, window-batch).  K/V staged in LDS, one row
// per lane, softmax without max-subtraction (logits are O(1) here;
// masked entries are -100 -> exp == 0).
// =====================================================================
__global__ __launch_bounds__(256) void k_attn(
    const float* __restrict__ Qh, const float* __restrict__ Kh, const float* __restrict__ Vh,
    const float* __restrict__ biasT, const float* __restrict__ mask, float* __restrict__ ctx)
{
    __shared__ float Ks[LL * HDD];
    __shared__ float Vs[LL * HDD];
    const int h = blockIdx.x, bn = blockIdx.y;
    const size_t base = ((size_t)bn * NHH + h) * (LL * HDD);
    const int tid = threadIdx.x;

    {
        const float4* kg = (const float4*)(Kh + base);
        const float4* vg = (const float4*)(Vh + base);
        float4* ks4 = (float4*)Ks;
        float4* vs4 = (float4*)Vs;
        for (int f = tid; f < LL * 8; f += 256) { ks4[f] = kg[f]; vs4[f] = vg[f]; }
    }
    __syncthreads();

    const int i = tid;
    if (i >= LL) return;

    float4 qv[8], cv[8];
    {
        const float4* qp = (const float4*)(Qh + base + (size_t)i * HDD);
#pragma unroll
        for (int u = 0; u < 8; u++) { qv[u] = qp[u]; cv[u] = make_float4(0.f, 0.f, 0.f, 0.f); }
    }
    const float* bs = biasT + (size_t)h * LL * LL + i;
    const float* ms = mask + (size_t)(bn & (NWW - 1)) * LL * LL + i;

    float ssum = 0.f;
    for (int j = 0; j < LL; j++) {
        const float4* kr = (const float4*)(Ks + j * HDD);
        float dacc = 0.f;
#pragma unroll
        for (int u = 0; u < 8; u++) {
            float4 kv = kr[u];
            dacc += qv[u].x*kv.x + qv[u].y*kv.y + qv[u].z*kv.z + qv[u].w*kv.w;
        }
        float logit = dacc * 0.17677669529663687f + bs[(size_t)j * LL] + ms[(size_t)j * LL];
        float p = __expf(logit);
        ssum += p;
        const float4* vr = (const float4*)(Vs + j * HDD);
#pragma unroll
        for (int u = 0; u < 8; u++) {
            float4 vx = vr[u];
            cv[u].x += p * vx.x; cv[u].y += p * vx.y; cv[u].z += p * vx.z; cv[u].w += p * vx.w;
        }
    }
    float inv = 1.f / ssum;
    float4* op = (float4*)(ctx + ((size_t)bn * LL + i) * PP + h * HDD);
#pragma unroll
    for (int u = 0; u < 8; u++) {
        float4 rr;
        rr.x = cv[u].x * inv; rr.y = cv[u].y * inv; rr.z = cv[u].z * inv; rr.w = cv[u].w * inv;
        op[u] = rr;
    }
}

// =====================================================================
// K3/K4/K5: generic GEMM  Y[T][ND] = X[T][KD] @ W[KD][ND] + b  (opt GELU)
// tile 128 tokens x 128 cols, thread tile 8x8.
// =====================================================================
template <int KD, int ND, int GELU>
__global__ __launch_bounds__(256) void k_gemm(
    const float* __restrict__ X, const float* __restrict__ W,
    const float* __restrict__ bb, float* __restrict__ Y)
{
    __shared__ float xs[32][132];
    __shared__ float wt[32][132];
    const int tid = threadIdx.x;
    const int m0 = blockIdx.x * 128;
    const int c0 = blockIdx.y * 128;
    const int tx = tid & 15, ty = tid >> 4;

    float acc[8][8];
#pragma unroll
    for (int t = 0; t < 8; t++)
#pragma unroll
        for (int c = 0; c < 8; c++) acc[t][c] = 0.f;

    for (int kc = 0; kc < KD / 32; kc++) {
        __syncthreads();
        {
            int tok = tid >> 1, half = tid & 1;
            const float* gp = X + (size_t)(m0 + tok) * KD + kc * 32 + half * 16;
            float4 a0 = *(const float4*)(gp);
            float4 a1 = *(const float4*)(gp + 4);
            float4 a2 = *(const float4*)(gp + 8);
            float4 a3 = *(const float4*)(gp + 12);
            int kb = half * 16;
            xs[kb+ 0][tok] = a0.x; xs[kb+ 1][tok] = a0.y; xs[kb+ 2][tok] = a0.z; xs[kb+ 3][tok] = a0.w;
            xs[kb+ 4][tok] = a1.x; xs[kb+ 5][tok] = a1.y; xs[kb+ 6][tok] = a1.z; xs[kb+ 7][tok] = a1.w;
            xs[kb+ 8][tok] = a2.x; xs[kb+ 9][tok] = a2.y; xs[kb+10][tok] = a2.z; xs[kb+11][tok] = a2.w;
            xs[kb+12][tok] = a3.x; xs[kb+13][tok] = a3.y; xs[kb+14][tok] = a3.z; xs[kb+15][tok] = a3.w;
        }
        {
#pragma unroll
            for (int u = 0; u < 4; u++) {
                int f = u * 256 + tid;          // 1024 float4 = 32x128
                int k = f >> 5, c4 = f & 31;
                *((float4*)&wt[k][c4 * 4]) =
                    *((const float4*)(W + (size_t)(kc * 32 + k) * ND + c0 + c4 * 4));
            }
        }
        __syncthreads();
#pragma unroll 4
        for (int k = 0; k < 32; k++) {
            float4 xa = *((const float4*)&xs[k][tx * 8]);
            float4 xb = *((const float4*)&xs[k][tx * 8 + 4]);
            float4 wa = *((const float4*)&wt[k][ty * 8]);
            float4 wb = *((const float4*)&wt[k][ty * 8 + 4]);
            float x8[8] = {xa.x, xa.y, xa.z, xa.w, xb.x, xb.y, xb.z, xb.w};
            float w8[8] = {wa.x, wa.y, wa.z, wa.w, wb.x, wb.y, wb.z, wb.w};
#pragma unroll
            for (int t = 0; t < 8; t++)
#pragma unroll
                for (int c = 0; c < 8; c++) acc[t][c] += x8[t] * w8[c];
        }
    }

    float b8[8];
    {
        float4 b0 = *((const float4*)(bb + c0 + ty * 8));
        float4 b1 = *((const float4*)(bb + c0 + ty * 8 + 4));
        b8[0]=b0.x; b8[1]=b0.y; b8[2]=b0.z; b8[3]=b0.w;
        b8[4]=b1.x; b8[5]=b1.y; b8[6]=b1.z; b8[7]=b1.w;
    }
#pragma unroll
    for (int t = 0; t < 8; t++) {
        int m = m0 + tx * 8 + t;
        float v[8];
#pragma unroll
        for (int c = 0; c < 8; c++) {
            float x = acc[t][c] + b8[c];
            if (GELU) x = 0.5f * x * (1.f + erff(x * 0.70710678118654752f));
            v[c] = x;
        }
        float* yp = Y + (size_t)m * ND + c0 + ty * 8;
        float4 r0, r1;
        r0.x=v[0]; r0.y=v[1]; r0.z=v[2]; r0.w=v[3];
        r1.x=v[4]; r1.y=v[5]; r1.z=v[6]; r1.w=v[7];
        *((float4*)yp) = r0;
        *((float4*)(yp + 4)) = r1;
    }
}

// =====================================================================
// LN (+residual add).  One wave per row of 128.
// =====================================================================
__global__ __launch_bounds__(256) void k_ln_add(
    const float* __restrict__ X, const float* __restrict__ gg, const float* __restrict__ bb,
    const float* __restrict__ res, float* __restrict__ Y)
{
    const int row = blockIdx.x * 4 + (threadIdx.x >> 6);
    const int lane = threadIdx.x & 63;
    const float2 v = ((const float2*)(X + (size_t)row * CC))[lane];
    float s = v.x + v.y, s2 = v.x * v.x + v.y * v.y;
#pragma unroll
    for (int m = 1; m < 64; m <<= 1) { s += __shfl_xor(s, m); s2 += __shfl_xor(s2, m); }
    const float mean = s * 0.0078125f;
    const float var  = s2 * 0.0078125f - mean * mean;
    const float rinv = rsqrtf(var + 1e-5f);
    const float2 g2 = ((const float2*)gg)[lane];
    const float2 b2 = ((const float2*)bb)[lane];
    const float2 r2 = ((const float2*)(res + (size_t)row * CC))[lane];
    float2 o;
    o.x = (v.x - mean) * rinv * g2.x + b2.x + r2.x;
    o.y = (v.y - mean) * rinv * g2.y + b2.y + r2.y;
    ((float2*)(Y + (size_t)row * CC))[lane] = o;
}

// =====================================================================
// LN2 + residual + reverse-partition + roll(+2,+3,+3) scatter to output
// =====================================================================
__global__ __launch_bounds__(256) void k_ln2_scatter(
    const float* __restrict__ X, const float* __restrict__ gg, const float* __restrict__ bb,
    const float* __restrict__ res, float* __restrict__ out)
{
    const int row = blockIdx.x * 4 + (threadIdx.x >> 6);
    const int lane = threadIdx.x & 63;
    const float2 v = ((const float2*)(X + (size_t)row * CC))[lane];
    float s = v.x + v.y, s2 = v.x * v.x + v.y * v.y;
#pragma unroll
    for (int m = 1; m < 64; m <<= 1) { s += __shfl_xor(s, m); s2 += __shfl_xor(s2, m); }
    const float mean = s * 0.0078125f;
    const float var  = s2 * 0.0078125f - mean * mean;
    const float rinv = rsqrtf(var + 1e-5f);
    const float2 g2 = ((const float2*)gg)[lane];
    const float2 b2 = ((const float2*)bb)[lane];
    const float2 r2 = ((const float2*)(res + (size_t)row * CC))[lane];
    float2 o;
    o.x = (v.x - mean) * rinv * g2.x + b2.x + r2.x;
    o.y = (v.y - mean) * rinv * g2.y + b2.y + r2.y;

    int l = row % LL, bw = row / LL;
    int w = bw & (NWW - 1), b = bw >> 7;
    int wd = w >> 6, wh = (w >> 3) & 7, ww = w & 7;
    int td = l / 49, r = l % 49, th = r / 7, tw = r % 7;
    int d  = wd * 4 + td + 2;  if (d  >= DV) d  -= DV;
    int hh = wh * 7 + th + 3;  if (hh >= HV) hh -= HV;
    int wc = ww * 7 + tw + 3;  if (wc >= WV) wc -= WV;
    size_t dest = (((size_t)(b * DV + d) * HV + hh) * WV + wc) * CC;
    ((float2*)(out + dest))[lane] = o;
}

// =====================================================================
extern "C" void kernel_launch(void* const* d_in, const int* in_sizes, int n_in,
                              void* d_out, int out_size, void* d_ws, size_t ws_size,
                              hipStream_t stream)
{
    (void)in_sizes; (void)n_in; (void)out_size;
    const float* q    = (const float*)d_in[0];
    const float* k    = (const float*)d_in[1];
    const float* v    = (const float*)d_in[2];
    const float* Wq   = (const float*)d_in[3];
    const float* bq   = (const float*)d_in[4];
    const float* Wk   = (const float*)d_in[5];
    const float* bk   = (const float*)d_in[6];
    const float* Wv   = (const float*)d_in[7];
    const float* bv   = (const float*)d_in[8];
    const float* Wo   = (const float*)d_in[9];
    const float* bo   = (const float*)d_in[10];
    const float* rtab = (const float*)d_in[11];
    const float* g1   = (const float*)d_in[12];
    const float* b1n  = (const float*)d_in[13];
    const float* W1   = (const float*)d_in[14];
    const float* b1m  = (const float*)d_in[15];
    const float* W2   = (const float*)d_in[16];
    const float* b2m  = (const float*)d_in[17];
    const float* g2   = (const float*)d_in[18];
    const float* b2n  = (const float*)d_in[19];
    const int*   ridx = (const int*)d_in[20];
    const float* msk  = (const float*)d_in[21];
    float* out = (float*)d_out;
    float* ws  = (float*)d_ws;

    const size_t TC = (size_t)TT * CC;        // 6,422,528
    const size_t TP = (size_t)TT * PP;        // 12,845,056
    const size_t BIAS = (size_t)NHH * LL * LL;

    float* resid = ws;                 // [T][C]
    float* Qb    = ws + TC;            // [Bn][NH][L][HD]
    float* Kb    = Qb + TP;
    float* Vb    = Kb + TP;
    float* ctxb  = Vb + TP;            // [Bn][L][P]
    float* biasT = ctxb + TP;          // [NH][L][L]
    // reuse after attention / projections:
    float* proj1 = Qb;                 // [T][C]   (Q dead after attn)
    float* h2    = Qb + TC;            // [T][C]
    float* attnb = Kb;                 // [T][C]   (K dead after attn)
    float* h1    = Vb;                 // [T][HID] (V+ctx dead after K3)

    const size_t need = (TC + 4 * TP + BIAS) * sizeof(float);
    if (ws_size < need) return;  // workspace too small; bench will flag incorrect

    k_bias<<<dim3((NHH * LL * LL + 255) / 256), dim3(256), 0, stream>>>(rtab, ridx, biasT);
    k_qkv<<<dim3(TT / 128, 3), dim3(256), 0, stream>>>(q, k, v, Wq, bq, Wk, bk, Wv, bv,
                                                       Qb, Kb, Vb, resid);
    k_attn<<<dim3(NHH, BNN), dim3(256), 0, stream>>>(Qb, Kb, Vb, biasT, msk, ctxb);
    k_gemm<PP, CC, 0><<<dim3(TT / 128, 1), dim3(256), 0, stream>>>(ctxb, Wo, bo, proj1);
    k_ln_add<<<dim3(TT / 4), dim3(256), 0, stream>>>(proj1, g1, b1n, resid, attnb);
    k_gemm<CC, HIDD, 1><<<dim3(TT / 128, 3), dim3(256), 0, stream>>>(attnb, W1, b1m, h1);
    k_gemm<HIDD, CC, 0><<<dim3(TT / 128, 1), dim3(256), 0, stream>>>(h1, W2, b2m, h2);
    k_ln2_scatter<<<dim3(TT / 4), dim3(256), 0, stream>>>(h2, g2, b2n, attnb, out);
}